// Round 1
// baseline (445.815 us; speedup 1.0000x reference)
//
#include <hip/hip_runtime.h>

#define HH 256
#define WW 256
#define HWPX 65536
#define BB 8
#define KK 21
#define CC 32

// ---------------- kernel 1: T[b,p] = sum_k S[b,k,p] ----------------
__global__ __launch_bounds__(256) void class_sum(const float* __restrict__ cls,
                                                 float* __restrict__ T) {
    int idx = blockIdx.x * 256 + threadIdx.x;   // b*HWPX + p
    int b = idx >> 16;
    int p = idx & (HWPX - 1);
    const float* base = cls + (size_t)b * KK * HWPX + p;
    float s = 0.f;
#pragma unroll
    for (int k = 0; k < KK; ++k) s += base[(size_t)k * HWPX];
    T[idx] = s;
}

// ---------------- kernel 2 (hot): degree + V per pixel ----------------
__global__ __launch_bounds__(256) void affinity(const float* __restrict__ feat,
                                                const float* __restrict__ T,
                                                float* __restrict__ V,
                                                float* __restrict__ deg) {
    int idx = blockIdx.x * 256 + threadIdx.x;   // b*HWPX + p
    int b = idx >> 16;
    int p = idx & (HWPX - 1);
    int h = p >> 8;
    int w = p & (WW - 1);
    const float* fb = feat + (size_t)b * CC * HWPX;

    float fp[CC];
#pragma unroll
    for (int c = 0; c < CC; ++c) fp[c] = fb[(size_t)c * HWPX + p];

    const float* Tb = T + b * HWPX;
    float degree = 0.f, v = 0.f;

#pragma unroll 1
    for (int dy = -4; dy <= 4; ++dy) {
        int h2 = h + dy;
        if ((unsigned)h2 >= HH) continue;       // wave-uniform (h uniform per wave)
#pragma unroll
        for (int dx = -4; dx <= 4; ++dx) {
            if (dy * dy + dx * dx >= 25) continue;  // compile-time prune
            int w2 = w + dx;
            if ((unsigned)w2 >= WW) continue;
            int p2 = h2 * WW + w2;
            float d2 = 0.f;
#pragma unroll
            for (int c = 0; c < CC; ++c) {
                float df = fp[c] - fb[(size_t)c * HWPX + p2];
                d2 = fmaf(df, df, d2);
            }
            // inv_sd2 = 1/16, inv_sf2 = 1
            float wgt = __expf(-(float)(dy * dy + dx * dx) * 0.0625f - d2);
            degree += wgt;
            v = fmaf(wgt, Tb[p2], v);
        }
    }
    V[idx] = v;
    deg[idx] = degree;
}

// ---------------- kernel 3: per-(b,j) numer/denom reduction ----------------
__global__ __launch_bounds__(256) void reduce_bj(const float* __restrict__ cls,
                                                 const float* __restrict__ V,
                                                 const float* __restrict__ deg,
                                                 float* __restrict__ numer,
                                                 float* __restrict__ denom) {
    int b = blockIdx.y;
    int start = blockIdx.x * 256 + threadIdx.x;
    int stride = gridDim.x * 256;

    float accN[KK], accD[KK];
#pragma unroll
    for (int j = 0; j < KK; ++j) { accN[j] = 0.f; accD[j] = 0.f; }

    const float* clsb = cls + (size_t)b * KK * HWPX;
    const float* Vb = V + b * HWPX;
    const float* db = deg + b * HWPX;

    for (int p = start; p < HWPX; p += stride) {
        float v = Vb[p];
        float dg = db[p];
#pragma unroll
        for (int j = 0; j < KK; ++j) {
            float s = clsb[(size_t)j * HWPX + p];
            accN[j] = fmaf(s, v, accN[j]);
            accD[j] = fmaf(s, dg, accD[j]);
        }
    }

#pragma unroll
    for (int j = 0; j < KK; ++j) {
        float n = accN[j], d = accD[j];
#pragma unroll
        for (int off = 32; off > 0; off >>= 1) {
            n += __shfl_down(n, off);
            d += __shfl_down(d, off);
        }
        if ((threadIdx.x & 63) == 0) {
            atomicAdd(&numer[b * KK + j], n);
            atomicAdd(&denom[b * KK + j], d);
        }
    }
}

// ---------------- kernel 4: out = sum_{b,j} numer/denom ----------------
__global__ __launch_bounds__(256) void finalize(const float* __restrict__ numer,
                                                const float* __restrict__ denom,
                                                float* __restrict__ out) {
    __shared__ float sm[4];
    int i = threadIdx.x;
    float r = 0.f;
    if (i < BB * KK) r = numer[i] / denom[i];
#pragma unroll
    for (int off = 32; off > 0; off >>= 1) r += __shfl_down(r, off);
    if ((i & 63) == 0) sm[i >> 6] = r;
    __syncthreads();
    if (i == 0) out[0] = sm[0] + sm[1] + sm[2] + sm[3];
}

extern "C" void kernel_launch(void* const* d_in, const int* in_sizes, int n_in,
                              void* d_out, int out_size, void* d_ws, size_t ws_size,
                              hipStream_t stream) {
    const float* cls  = (const float*)d_in[0];  // [B,K,H,W] = 11,010,048 floats
    const float* feat = (const float*)d_in[1];  // [B,C,H,W] = 16,777,216 floats
    float* out = (float*)d_out;

    // workspace layout (floats):
    //   T:      [B*HWPX]            @ 0
    //   V:      [B*HWPX]            @ 1*BHW
    //   deg:    [B*HWPX]            @ 2*BHW
    //   numer:  [B*K]               @ 3*BHW
    //   denom:  [B*K]               @ 3*BHW + B*K
    const size_t BHW = (size_t)BB * HWPX;
    float* T     = (float*)d_ws;
    float* V     = T + BHW;
    float* deg   = V + BHW;
    float* numer = deg + BHW;
    float* denom = numer + BB * KK;

    // zero the atomic accumulators (ws is poisoned with 0xAA before each call)
    hipMemsetAsync(numer, 0, 2 * BB * KK * sizeof(float), stream);

    class_sum<<<dim3(BB * HWPX / 256), dim3(256), 0, stream>>>(cls, T);
    affinity<<<dim3(BB * HWPX / 256), dim3(256), 0, stream>>>(feat, T, V, deg);
    reduce_bj<<<dim3(32, BB), dim3(256), 0, stream>>>(cls, V, deg, numer, denom);
    finalize<<<dim3(1), dim3(256), 0, stream>>>(numer, denom, out);
}